// Round 1
// baseline (348.673 us; speedup 1.0000x reference)
//
#include <hip/hip_runtime.h>
#include <hip/hip_bf16.h>

typedef __attribute__((ext_vector_type(8))) short short8;
typedef __attribute__((ext_vector_type(4))) float f32x4;

#define BM 128
#define BN 128
#define BK 32
#define NDIM 1024
#define INDIM 1024
#define KEXP 8
#define LDW 40          // padded LDS row length in ushorts (32 data + 8 pad)
#define NTILES 256      // KEXP * INDIM / BK

__device__ __forceinline__ unsigned int pack2bf(float a, float b) {
    __hip_bfloat162 h = __float22bfloat162_rn(make_float2(a, b));
    union { __hip_bfloat162 h; unsigned int u; } cv;
    cv.h = h;
    return cv.u;
}

__global__ __launch_bounds__(256, 2)
void moe_blend_gemm(const float* __restrict__ x,
                    const float* __restrict__ ew,
                    const float* __restrict__ w,
                    const float* __restrict__ bias,
                    float* __restrict__ out) {
    __shared__ unsigned short lA[BM][LDW];
    __shared__ unsigned short lB[BN][LDW];

    const int tid = threadIdx.x;
    const int bid = blockIdx.x;
    const int nt = bid & 7;          // N-tile == XCD (round-robin dispatch heuristic)
    const int mt = bid >> 3;
    const int mbase = mt * BM;
    const int nbase = nt * BN;

    // staging coords: each thread owns half a 32-wide row (16 f32)
    const int trow = tid >> 1;
    const int tcol = (tid & 1) * 16;

    const float* xp = x + (size_t)(mbase + trow) * INDIM + tcol;
    const float* wp = w + (size_t)(nbase + trow) * INDIM + tcol;
    const float* ep = ew + (size_t)(mbase + trow) * KEXP;

    // compute coords: 4 waves in 2x2, each owns 64x64
    const int wid = tid >> 6;
    const int wrB = (wid >> 1) * 64;
    const int wcB = (wid & 1) * 64;
    const int l = tid & 63;
    const int lr = l & 15;
    const int lg = l >> 4;

    f32x4 acc[4][4];
#pragma unroll
    for (int m = 0; m < 4; ++m)
#pragma unroll
        for (int n = 0; n < 4; ++n) acc[m][n] = f32x4{0.f, 0.f, 0.f, 0.f};

    const unsigned short* rdA = &lA[wrB + lr][lg * 8];
    const unsigned short* rdB = &lB[wcB + lr][lg * 8];
    unsigned int* wA = (unsigned int*)&lA[trow][tcol];
    unsigned int* wB = (unsigned int*)&lB[trow][tcol];

    float4 ra0, ra1, ra2, ra3, rb0, rb1, rb2, rb3;
    float sc;

    {   // prefetch tile 0 into registers
        const float4* pa = (const float4*)(xp);
        ra0 = pa[0]; ra1 = pa[1]; ra2 = pa[2]; ra3 = pa[3];
        const float4* pb = (const float4*)(wp);
        rb0 = pb[0]; rb1 = pb[1]; rb2 = pb[2]; rb3 = pb[3];
        sc = ep[0];
    }

    for (int tt = 0; tt < NTILES; ++tt) {
        __syncthreads();
        {   // scale (A only) + convert f32->bf16 + write LDS (2x b128 per matrix)
            uint4 qa0, qa1, qb0, qb1;
            qa0.x = pack2bf(ra0.x * sc, ra0.y * sc);
            qa0.y = pack2bf(ra0.z * sc, ra0.w * sc);
            qa0.z = pack2bf(ra1.x * sc, ra1.y * sc);
            qa0.w = pack2bf(ra1.z * sc, ra1.w * sc);
            qa1.x = pack2bf(ra2.x * sc, ra2.y * sc);
            qa1.y = pack2bf(ra2.z * sc, ra2.w * sc);
            qa1.z = pack2bf(ra3.x * sc, ra3.y * sc);
            qa1.w = pack2bf(ra3.z * sc, ra3.w * sc);
            qb0.x = pack2bf(rb0.x, rb0.y);
            qb0.y = pack2bf(rb0.z, rb0.w);
            qb0.z = pack2bf(rb1.x, rb1.y);
            qb0.w = pack2bf(rb1.z, rb1.w);
            qb1.x = pack2bf(rb2.x, rb2.y);
            qb1.y = pack2bf(rb2.z, rb2.w);
            qb1.z = pack2bf(rb3.x, rb3.y);
            qb1.w = pack2bf(rb3.z, rb3.w);
            *(uint4*)(wA)     = qa0;
            *(uint4*)(wA + 4) = qa1;
            *(uint4*)(wB)     = qb0;
            *(uint4*)(wB + 4) = qb1;
        }
        __syncthreads();

        if (tt + 1 < NTILES) {  // prefetch next tile; latency hides under MFMA below
            const int kc = (tt + 1) >> 5;
            const int i0 = ((tt + 1) & 31) * BK;
            const float4* pa = (const float4*)(xp + i0);
            ra0 = pa[0]; ra1 = pa[1]; ra2 = pa[2]; ra3 = pa[3];
            const float4* pb = (const float4*)(wp + (size_t)kc * (size_t)(NDIM * INDIM) + i0);
            rb0 = pb[0]; rb1 = pb[1]; rb2 = pb[2]; rb3 = pb[3];
            sc = ep[kc];
        }

        {   // 8 ds_read_b128 + 16 MFMA per wave
            short8 af0 = *(const short8*)(rdA + 0 * 16 * LDW);
            short8 af1 = *(const short8*)(rdA + 1 * 16 * LDW);
            short8 af2 = *(const short8*)(rdA + 2 * 16 * LDW);
            short8 af3 = *(const short8*)(rdA + 3 * 16 * LDW);
            short8 bf0 = *(const short8*)(rdB + 0 * 16 * LDW);
            short8 bf1 = *(const short8*)(rdB + 1 * 16 * LDW);
            short8 bf2 = *(const short8*)(rdB + 2 * 16 * LDW);
            short8 bf3 = *(const short8*)(rdB + 3 * 16 * LDW);
            short8 af[4] = {af0, af1, af2, af3};
            short8 bf[4] = {bf0, bf1, bf2, bf3};
#pragma unroll
            for (int m = 0; m < 4; ++m)
#pragma unroll
                for (int n = 0; n < 4; ++n)
                    acc[m][n] = __builtin_amdgcn_mfma_f32_16x16x32_bf16(
                        af[m], bf[n], acc[m][n], 0, 0, 0);
        }
    }

    // epilogue: exact bias term  y += sum_k ew[b,k]*bias[k,o]  (bias happens to be 0
    // in this benchmark but is handled for generality; runs once, negligible)
    float bv[4][8];
#pragma unroll
    for (int n = 0; n < 4; ++n) {
        const int gc = nbase + wcB + n * 16 + lr;
#pragma unroll
        for (int k = 0; k < 8; ++k) bv[n][k] = bias[k * NDIM + gc];
    }

#pragma unroll
    for (int m = 0; m < 4; ++m) {
#pragma unroll
        for (int j = 0; j < 4; ++j) {
            const int gr = mbase + wrB + m * 16 + lg * 4 + j;
            const float4* e4 = (const float4*)(ew + (size_t)gr * KEXP);
            const float4 e0 = e4[0];
            const float4 e1 = e4[1];
            const float eb[8] = {e0.x, e0.y, e0.z, e0.w, e1.x, e1.y, e1.z, e1.w};
            float* op = out + (size_t)gr * NDIM + nbase + wcB;
#pragma unroll
            for (int n = 0; n < 4; ++n) {
                float t = acc[m][n][j];
#pragma unroll
                for (int k = 0; k < 8; ++k) t += eb[k] * bv[n][k];
                op[n * 16 + lr] = t;
            }
        }
    }
}

extern "C" void kernel_launch(void* const* d_in, const int* in_sizes, int n_in,
                              void* d_out, int out_size, void* d_ws, size_t ws_size,
                              hipStream_t stream) {
    (void)in_sizes; (void)n_in; (void)out_size; (void)d_ws; (void)ws_size;
    const float* x    = (const float*)d_in[0];
    const float* ew   = (const float*)d_in[1];
    const float* w    = (const float*)d_in[2];
    const float* bias = (const float*)d_in[3];
    float* out = (float*)d_out;

    dim3 grid(512);   // 64 m-tiles x 8 n-tiles; bid&7 = n-tile = XCD
    dim3 block(256);
    hipLaunchKernelGGL(moe_blend_gemm, grid, block, 0, stream, x, ew, w, bias, out);
}

// Round 2
// 304.226 us; speedup vs baseline: 1.1461x; 1.1461x over previous
//
#include <hip/hip_runtime.h>
#include <hip/hip_bf16.h>

typedef __attribute__((ext_vector_type(8))) short short8;
typedef __attribute__((ext_vector_type(4))) float f32x4;

#define NDIM 1024
#define INDIM 1024
#define KEXP 8
#define BROWS 8192
#define NX (BROWS * INDIM)        // x elements   (8388608)
#define NW (KEXP * NDIM * INDIM)  // w elements   (8388608)

__device__ __forceinline__ unsigned int pack2bf(float a, float b) {
    __hip_bfloat162 h = __float22bfloat162_rn(make_float2(a, b));
    union { __hip_bfloat162 h; unsigned int u; } cv;
    cv.h = h;
    return cv.u;
}

__device__ __forceinline__ void gload16(const void* src, void* ldsdst) {
    __builtin_amdgcn_global_load_lds(
        (__attribute__((address_space(1))) void*)(src),
        (__attribute__((address_space(3))) void*)(ldsdst), 16, 0, 0);
}

// ---------------- kernel 1: f32 -> bf16 convert of x and W into ws ----------------
__global__ void convert_bf16(const float* __restrict__ x, const float* __restrict__ w,
                             unsigned short* __restrict__ dst) {
    const long total = (long)NX + NW;
    const long stride = (long)gridDim.x * blockDim.x * 8;
    for (long i = ((long)blockIdx.x * blockDim.x + threadIdx.x) * 8; i < total; i += stride) {
        const float* s = (i < NX) ? (x + i) : (w + (i - NX));
        float4 a = ((const float4*)s)[0];
        float4 b = ((const float4*)s)[1];
        uint4 q;
        q.x = pack2bf(a.x, a.y); q.y = pack2bf(a.z, a.w);
        q.z = pack2bf(b.x, b.y); q.w = pack2bf(b.z, b.w);
        *(uint4*)(dst + i) = q;
    }
}

// ---------------- kernel 2: expert-blocked bf16 GEMM with f32 register blend -------
// tile 64x128, BK=32, 4 waves (each 32x64), global_load_lds staging, XOR-swizzled LDS
#define BM 64
#define BN 128
#define BK 32

__global__ __launch_bounds__(256, 3)
void moe_gemm_bf16(const unsigned short* __restrict__ ab,   // A' bf16 x at 0, B' bf16 w at NX
                   const float* __restrict__ ew,
                   const float* __restrict__ bias,
                   float* __restrict__ out) {
    __shared__ unsigned short lds[2][BM * BK + BN * BK];   // 2 x 6144 ushorts = 24 KB

    const int tid = threadIdx.x;
    const int bid = blockIdx.x;
    const int nt = bid & 7;            // n-tile == XCD (L2-pins the 2MB W column panel)
    const int mt = bid >> 3;           // 0..127
    const int mbase = mt * BM;
    const int nbase = nt * BN;

    const int w = tid >> 6;
    const int l = tid & 63;
    const int lr = l & 15;
    const int lg = l >> 4;
    const int wrB = (w >> 1) * 32;     // wave row base within tile (0 / 32)
    const int wcB = (w & 1) * 64;      // wave col base within tile (0 / 64)

    // staging lane coords: chunk = 16 rows x 32 cols bf16 = 1024B = 64 lanes x 16B
    const int rowin = l >> 2;                    // 0..15
    const int slot = (l & 3) ^ ((l >> 3) & 3);   // pre-swizzled 16B slot (involution)

    const unsigned short* Abase = ab + (size_t)mbase * INDIM;
    const unsigned short* Bbase = ab + NX + (size_t)nbase * INDIM;

    f32x4 acc[2][4], accT[2][4];
#pragma unroll
    for (int m = 0; m < 2; ++m)
#pragma unroll
        for (int n = 0; n < 4; ++n) {
            acc[m][n] = f32x4{0.f, 0.f, 0.f, 0.f};
            accT[m][n] = f32x4{0.f, 0.f, 0.f, 0.f};
        }

    // ds_read offsets (ushort units), same XOR involution as the staged source
    const int swz = (lr >> 1) & 3;
    int aoff[2], boff[4];
#pragma unroll
    for (int m = 0; m < 2; ++m)
        aoff[m] = (wrB + m * 16 + lr) * BK + ((lg ^ swz) * 8);
#pragma unroll
    for (int n = 0; n < 4; ++n)
        boff[n] = BM * BK + (wcB + n * 16 + lr) * BK + ((lg ^ swz) * 8);

    // stage one K-step tile (A 4 chunks + B 8 chunks; 3 chunks per wave)
    auto stage = [&](int buf, int k, int it) {
        unsigned short* lbase = &lds[buf][0];
        const int col = it * BK + slot * 8;
#pragma unroll
        for (int i = 0; i < 3; ++i) {
            const int c = w * 3 + i;
            if (c < 4) {
                gload16(Abase + (size_t)(c * 16 + rowin) * INDIM + col, lbase + c * 512);
            } else {
                const int cb = c - 4;
                gload16(Bbase + (size_t)k * (NDIM * INDIM) + (size_t)(cb * 16 + rowin) * INDIM + col,
                        lbase + BM * BK + cb * 512);
            }
        }
    };

    stage(0, 0, 0);
    __syncthreads();

    for (int k = 0; k < KEXP; ++k) {
        for (int it = 0; it < 32; ++it) {
            const int t = k * 32 + it;
            const int cur = t & 1;
            if (t + 1 < KEXP * 32) stage(cur ^ 1, (t + 1) >> 5, (t + 1) & 31);

            const unsigned short* lb = &lds[cur][0];
            short8 af[2], bf[4];
#pragma unroll
            for (int m = 0; m < 2; ++m) af[m] = *(const short8*)(lb + aoff[m]);
#pragma unroll
            for (int n = 0; n < 4; ++n) bf[n] = *(const short8*)(lb + boff[n]);
#pragma unroll
            for (int m = 0; m < 2; ++m)
#pragma unroll
                for (int n = 0; n < 4; ++n)
                    acc[m][n] = __builtin_amdgcn_mfma_f32_16x16x32_bf16(
                        af[m], bf[n], acc[m][n], 0, 0, 0);
            __syncthreads();
        }
        // expert k finished: blend per-expert result into total with routing weight (f32 exact)
        float e[2][4];
#pragma unroll
        for (int m = 0; m < 2; ++m)
#pragma unroll
            for (int j = 0; j < 4; ++j)
                e[m][j] = ew[(size_t)(mbase + wrB + m * 16 + lg * 4 + j) * KEXP + k];
#pragma unroll
        for (int m = 0; m < 2; ++m)
#pragma unroll
            for (int n = 0; n < 4; ++n)
#pragma unroll
                for (int j = 0; j < 4; ++j) {
                    accT[m][n][j] += e[m][j] * acc[m][n][j];
                    if (n == 3 && true) {}
                }
#pragma unroll
        for (int m = 0; m < 2; ++m)
#pragma unroll
            for (int n = 0; n < 4; ++n) acc[m][n] = f32x4{0.f, 0.f, 0.f, 0.f};
    }

    // epilogue: out = accT + sum_k ew*bias (bias is 0 in this bench; exact for generality)
    float bv[4][8];
#pragma unroll
    for (int n = 0; n < 4; ++n) {
        const int gc = nbase + wcB + n * 16 + lr;
#pragma unroll
        for (int kk = 0; kk < 8; ++kk) bv[n][kk] = bias[kk * NDIM + gc];
    }
#pragma unroll
    for (int m = 0; m < 2; ++m)
#pragma unroll
        for (int j = 0; j < 4; ++j) {
            const int grow = mbase + wrB + m * 16 + lg * 4 + j;
            const float4* e4 = (const float4*)(ew + (size_t)grow * KEXP);
            const float4 e0 = e4[0];
            const float4 e1 = e4[1];
            const float eb[8] = {e0.x, e0.y, e0.z, e0.w, e1.x, e1.y, e1.z, e1.w};
            float* op = out + (size_t)grow * NDIM + nbase + wcB;
#pragma unroll
            for (int n = 0; n < 4; ++n) {
                float t = accT[m][n][j];
#pragma unroll
                for (int kk = 0; kk < 8; ++kk) t += eb[kk] * bv[n][kk];
                op[n * 16 + lr] = t;
            }
        }
}

// ---------------- fallback (round-1 kernel) if ws is too small --------------------
#define FLDW 40
__global__ __launch_bounds__(256, 2)
void moe_blend_gemm_fb(const float* __restrict__ x, const float* __restrict__ ew,
                       const float* __restrict__ w, const float* __restrict__ bias,
                       float* __restrict__ out) {
    __shared__ unsigned short lA[128][FLDW];
    __shared__ unsigned short lB[128][FLDW];
    const int tid = threadIdx.x, bid = blockIdx.x;
    const int nt = bid & 7, mt = bid >> 3;
    const int mbase = mt * 128, nbase = nt * 128;
    const int trow = tid >> 1, tcol = (tid & 1) * 16;
    const float* xp = x + (size_t)(mbase + trow) * INDIM + tcol;
    const float* wp = w + (size_t)(nbase + trow) * INDIM + tcol;
    const float* ep = ew + (size_t)(mbase + trow) * KEXP;
    const int wid = tid >> 6, wrB = (wid >> 1) * 64, wcB = (wid & 1) * 64;
    const int l = tid & 63, lr = l & 15, lg = l >> 4;
    f32x4 acc[4][4];
#pragma unroll
    for (int m = 0; m < 4; ++m)
#pragma unroll
        for (int n = 0; n < 4; ++n) acc[m][n] = f32x4{0.f, 0.f, 0.f, 0.f};
    const unsigned short* rdA = &lA[wrB + lr][lg * 8];
    const unsigned short* rdB = &lB[wcB + lr][lg * 8];
    unsigned int* wA = (unsigned int*)&lA[trow][tcol];
    unsigned int* wB = (unsigned int*)&lB[trow][tcol];
    float4 ra0, ra1, ra2, ra3, rb0, rb1, rb2, rb3;
    float sc;
    {
        const float4* pa = (const float4*)(xp);
        ra0 = pa[0]; ra1 = pa[1]; ra2 = pa[2]; ra3 = pa[3];
        const float4* pb = (const float4*)(wp);
        rb0 = pb[0]; rb1 = pb[1]; rb2 = pb[2]; rb3 = pb[3];
        sc = ep[0];
    }
    for (int tt = 0; tt < 256; ++tt) {
        __syncthreads();
        uint4 qa0, qa1, qb0, qb1;
        qa0.x = pack2bf(ra0.x * sc, ra0.y * sc); qa0.y = pack2bf(ra0.z * sc, ra0.w * sc);
        qa0.z = pack2bf(ra1.x * sc, ra1.y * sc); qa0.w = pack2bf(ra1.z * sc, ra1.w * sc);
        qa1.x = pack2bf(ra2.x * sc, ra2.y * sc); qa1.y = pack2bf(ra2.z * sc, ra2.w * sc);
        qa1.z = pack2bf(ra3.x * sc, ra3.y * sc); qa1.w = pack2bf(ra3.z * sc, ra3.w * sc);
        qb0.x = pack2bf(rb0.x, rb0.y); qb0.y = pack2bf(rb0.z, rb0.w);
        qb0.z = pack2bf(rb1.x, rb1.y); qb0.w = pack2bf(rb1.z, rb1.w);
        qb1.x = pack2bf(rb2.x, rb2.y); qb1.y = pack2bf(rb2.z, rb2.w);
        qb1.z = pack2bf(rb3.x, rb3.y); qb1.w = pack2bf(rb3.z, rb3.w);
        *(uint4*)(wA) = qa0; *(uint4*)(wA + 4) = qa1;
        *(uint4*)(wB) = qb0; *(uint4*)(wB + 4) = qb1;
        __syncthreads();
        if (tt + 1 < 256) {
            const int kc = (tt + 1) >> 5, i0 = ((tt + 1) & 31) * 32;
            const float4* pa = (const float4*)(xp + i0);
            ra0 = pa[0]; ra1 = pa[1]; ra2 = pa[2]; ra3 = pa[3];
            const float4* pb = (const float4*)(wp + (size_t)kc * (size_t)(NDIM * INDIM) + i0);
            rb0 = pb[0]; rb1 = pb[1]; rb2 = pb[2]; rb3 = pb[3];
            sc = ep[kc];
        }
        short8 af[4], bf[4];
#pragma unroll
        for (int m = 0; m < 4; ++m) af[m] = *(const short8*)(rdA + m * 16 * FLDW);
#pragma unroll
        for (int n = 0; n < 4; ++n) bf[n] = *(const short8*)(rdB + n * 16 * FLDW);
#pragma unroll
        for (int m = 0; m < 4; ++m)
#pragma unroll
            for (int n = 0; n < 4; ++n)
                acc[m][n] = __builtin_amdgcn_mfma_f32_16x16x32_bf16(af[m], bf[n], acc[m][n], 0, 0, 0);
    }
#pragma unroll
    for (int m = 0; m < 4; ++m)
#pragma unroll
        for (int j = 0; j < 4; ++j) {
            const int gr = mbase + wrB + m * 16 + lg * 4 + j;
            const float4* e4 = (const float4*)(ew + (size_t)gr * KEXP);
            const float4 e0 = e4[0], e1 = e4[1];
            const float eb[8] = {e0.x, e0.y, e0.z, e0.w, e1.x, e1.y, e1.z, e1.w};
            float* op = out + (size_t)gr * NDIM + nbase + wcB;
#pragma unroll
            for (int n = 0; n < 4; ++n) {
                float t = acc[m][n][j];
#pragma unroll
                for (int kk = 0; kk < 8; ++kk) t += eb[kk] * bias[kk * NDIM + nbase + wcB + n * 16 + lr];
                op[n * 16 + lr] = t;
            }
        }
}

extern "C" void kernel_launch(void* const* d_in, const int* in_sizes, int n_in,
                              void* d_out, int out_size, void* d_ws, size_t ws_size,
                              hipStream_t stream) {
    (void)in_sizes; (void)n_in; (void)out_size;
    const float* x    = (const float*)d_in[0];
    const float* ew   = (const float*)d_in[1];
    const float* w    = (const float*)d_in[2];
    const float* bias = (const float*)d_in[3];
    float* out = (float*)d_out;

    const size_t need = (size_t)(NX + NW) * sizeof(unsigned short);  // 33.5 MB
    if (ws_size >= need) {
        unsigned short* ab = (unsigned short*)d_ws;
        hipLaunchKernelGGL(convert_bf16, dim3(2048), dim3(256), 0, stream, x, w, ab);
        hipLaunchKernelGGL(moe_gemm_bf16, dim3(1024), dim3(256), 0, stream, ab, ew, bias, out);
    } else {
        hipLaunchKernelGGL(moe_blend_gemm_fb, dim3(512), dim3(256), 0, stream, x, ew, w, bias, out);
    }
}

// Round 3
// 184.077 us; speedup vs baseline: 1.8942x; 1.6527x over previous
//
#include <hip/hip_runtime.h>
#include <hip/hip_bf16.h>

typedef __attribute__((ext_vector_type(8))) short short8;
typedef __attribute__((ext_vector_type(4))) float f32x4;

#define NDIM 1024
#define INDIM 1024
#define KEXP 8
#define BROWS 8192
#define NX (BROWS * INDIM)        // x elements   (8388608)
#define NW (KEXP * NDIM * INDIM)  // w elements   (8388608)

// GEMM geometry
#define BM 256
#define BN 128
#define BK 64
#define NT 128                    // K-tiles total: 8 experts * (1024/64)
#define ABUF 16384                // ushorts per A slab (2 ks * 256 rows * 32)
#define BBUF 8192                 // ushorts per B slab (2 ks * 128 rows * 32)
#define BUFU (ABUF + BBUF)        // 24576 ushorts = 48 KiB per ring slot

__device__ __forceinline__ unsigned int pack2bf(float a, float b) {
    __hip_bfloat162 h = __float22bfloat162_rn(make_float2(a, b));
    union { __hip_bfloat162 h; unsigned int u; } cv;
    cv.h = h;
    return cv.u;
}

__device__ __forceinline__ void gload16(const void* src, void* ldsdst) {
    __builtin_amdgcn_global_load_lds(
        (__attribute__((address_space(1))) void*)(src),
        (__attribute__((address_space(3))) void*)(ldsdst), 16, 0, 0);
}

// ---------------- kernel 1: f32 -> bf16 convert of x and W into ws ----------------
__global__ void convert_bf16(const float* __restrict__ x, const float* __restrict__ w,
                             unsigned short* __restrict__ dst) {
    const long total = (long)NX + NW;
    const long stride = (long)gridDim.x * blockDim.x * 8;
    for (long i = ((long)blockIdx.x * blockDim.x + threadIdx.x) * 8; i < total; i += stride) {
        const float* s = (i < NX) ? (x + i) : (w + (i - NX));
        float4 a = ((const float4*)s)[0];
        float4 b = ((const float4*)s)[1];
        uint4 q;
        q.x = pack2bf(a.x, a.y); q.y = pack2bf(a.z, a.w);
        q.z = pack2bf(b.x, b.y); q.w = pack2bf(b.z, b.w);
        *(uint4*)(dst + i) = q;
    }
}

// ------------- kernel 2: ring-3 counted-vmcnt 4-phase pipelined bf16 GEMM ----------
// 256x128 tile, BK=64, 8 waves (4M x 2N, wave tile 64x64), per-expert f32 blend.
__global__ __launch_bounds__(512, 2)
void moe_gemm_pipe(const unsigned short* __restrict__ ab,   // bf16: x at 0, w at NX
                   const float* __restrict__ ew,
                   const float* __restrict__ bias,
                   float* __restrict__ out) {
    __shared__ __align__(16) unsigned short lds[3 * BUFU];   // 144 KiB ring

    const int tid = threadIdx.x;
    const int bid = blockIdx.x;
    const int nt = bid & 7;            // n-tile == XCD: B panel (2 MB) stays L2-resident
    const int mt = bid >> 3;           // 0..31
    const int mbase = mt * BM;
    const int nbase = nt * BN;

    const int w  = tid >> 6;           // wave 0..7
    const int l  = tid & 63;
    const int lr = l & 15;
    const int lg = l >> 4;
    const int wrow = (w >> 1) * 64;    // 4 M-groups
    const int wcol = (w & 1) * 64;     // 2 N-groups

    // staging lane coords: chunk = 16 rows x 32 cols bf16 = 1024 B
    const int lrow = l >> 2;                     // row within chunk
    const int sg = (l & 3) ^ ((l >> 3) & 3);     // pre-swizzled 8-elem col block

    const unsigned short* Xb = ab;
    const unsigned short* Wb = ab + NX;

    // fragment read offsets (ushort units) with matching XOR involution
    const int swz = (lr >> 1) & 3;
    int aoff[4][2], boff[4][2];
#pragma unroll
    for (int m = 0; m < 4; ++m)
#pragma unroll
        for (int ks = 0; ks < 2; ++ks)
            aoff[m][ks] = ks * 8192 + (wrow + m * 16 + lr) * 32 + ((lg ^ swz) * 8);
#pragma unroll
    for (int n = 0; n < 4; ++n)
#pragma unroll
        for (int ks = 0; ks < 2; ++ks)
            boff[n][ks] = ABUF + ks * 4096 + (wcol + n * 16 + lr) * 32 + ((lg ^ swz) * 8);

    // stage helpers: wave-uniform LDS dest (global_load_lds scatters lane*16)
    auto stageA = [&](int buf, int kt, int i) {
        const int c = i * 8 + w;                  // 0..31
        const int ks = c >> 4, rg = c & 15;
        const unsigned short* src = Xb + (size_t)(mbase + rg * 16 + lrow) * INDIM
                                  + (size_t)((kt & 15) * 64 + ks * 32 + sg * 8);
        gload16(src, &lds[buf * BUFU + c * 512]);
    };
    auto stageB = [&](int buf, int kt, int i) {
        const int c = i * 8 + w;                  // 0..15
        const int ks = c >> 3, rg = c & 7;
        const unsigned short* src = Wb + (size_t)(kt >> 4) * (NDIM * INDIM)
                                  + (size_t)(nbase + rg * 16 + lrow) * INDIM
                                  + (size_t)((kt & 15) * 64 + ks * 32 + sg * 8);
        gload16(src, &lds[buf * BUFU + ABUF + c * 512]);
    };

    f32x4 acc[4][4], accT[4][4];
#pragma unroll
    for (int m = 0; m < 4; ++m)
#pragma unroll
        for (int n = 0; n < 4; ++n) {
            acc[m][n] = f32x4{0.f, 0.f, 0.f, 0.f};
            accT[m][n] = f32x4{0.f, 0.f, 0.f, 0.f};
        }

    // prologue: stage tiles 0,1 (6 vmem per wave each, in order)
#pragma unroll
    for (int t = 0; t < 2; ++t) {
        stageA(t, t, 0); stageA(t, t, 1); stageA(t, t, 2); stageA(t, t, 3);
        stageB(t, t, 0); stageB(t, t, 1);
    }

    int bufR = 0, bufS = 2;
#pragma unroll 1
    for (int kt = 0; kt < NT; ++kt) {
        const bool doS = (kt + 2) < NT;
        const bool bnd = (kt & 15) == 15;

        // tile gate: own stage(kt) landed (vmcnt<=6 leaves stage(kt+1) in flight),
        // then barrier makes every wave's staging visible. NEVER vmcnt(0) mid-loop.
        if (kt < NT - 2)
            asm volatile("s_waitcnt vmcnt(6)\n\ts_barrier" ::: "memory");
        else
            asm volatile("s_waitcnt vmcnt(0)\n\ts_barrier" ::: "memory");

        float e0[4][4];
        if (bnd) {
            const int eidx = kt >> 4;
#pragma unroll
            for (int m = 0; m < 4; ++m)
#pragma unroll
                for (int j = 0; j < 4; ++j)
                    e0[m][j] = ew[(size_t)(mbase + wrow + m * 16 + lg * 4 + j) * KEXP + eidx];
        }

        const unsigned short* lb = &lds[bufR * BUFU];
        short8 af[4], bf[4];

        // ---- P0: ks=0, m0-1 x n0-3
        af[0] = *(const short8*)(lb + aoff[0][0]);
        af[1] = *(const short8*)(lb + aoff[1][0]);
        bf[0] = *(const short8*)(lb + boff[0][0]);
        bf[1] = *(const short8*)(lb + boff[1][0]);
        bf[2] = *(const short8*)(lb + boff[2][0]);
        bf[3] = *(const short8*)(lb + boff[3][0]);
        if (doS) { stageA(bufS, kt + 2, 0); stageA(bufS, kt + 2, 1); }
        __builtin_amdgcn_s_setprio(1);
#pragma unroll
        for (int m = 0; m < 2; ++m)
#pragma unroll
            for (int n = 0; n < 4; ++n)
                acc[m][n] = __builtin_amdgcn_mfma_f32_16x16x32_bf16(af[m], bf[n], acc[m][n], 0, 0, 0);
        __builtin_amdgcn_s_setprio(0);
        __builtin_amdgcn_s_barrier();
        __builtin_amdgcn_sched_barrier(0);

        // ---- P1: ks=0, m2-3 (reuse bf)
        af[2] = *(const short8*)(lb + aoff[2][0]);
        af[3] = *(const short8*)(lb + aoff[3][0]);
        if (doS) { stageA(bufS, kt + 2, 2); stageA(bufS, kt + 2, 3); }
        __builtin_amdgcn_s_setprio(1);
#pragma unroll
        for (int m = 2; m < 4; ++m)
#pragma unroll
            for (int n = 0; n < 4; ++n)
                acc[m][n] = __builtin_amdgcn_mfma_f32_16x16x32_bf16(af[m], bf[n], acc[m][n], 0, 0, 0);
        __builtin_amdgcn_s_setprio(0);
        __builtin_amdgcn_s_barrier();
        __builtin_amdgcn_sched_barrier(0);

        // ---- P2: ks=1, m0-1
        af[0] = *(const short8*)(lb + aoff[0][1]);
        af[1] = *(const short8*)(lb + aoff[1][1]);
        bf[0] = *(const short8*)(lb + boff[0][1]);
        bf[1] = *(const short8*)(lb + boff[1][1]);
        bf[2] = *(const short8*)(lb + boff[2][1]);
        bf[3] = *(const short8*)(lb + boff[3][1]);
        if (doS) stageB(bufS, kt + 2, 0);
        __builtin_amdgcn_s_setprio(1);
#pragma unroll
        for (int m = 0; m < 2; ++m)
#pragma unroll
            for (int n = 0; n < 4; ++n)
                acc[m][n] = __builtin_amdgcn_mfma_f32_16x16x32_bf16(af[m], bf[n], acc[m][n], 0, 0, 0);
        __builtin_amdgcn_s_setprio(0);
        __builtin_amdgcn_s_barrier();
        __builtin_amdgcn_sched_barrier(0);

        // ---- P3: ks=1, m2-3
        af[2] = *(const short8*)(lb + aoff[2][1]);
        af[3] = *(const short8*)(lb + aoff[3][1]);
        if (doS) stageB(bufS, kt + 2, 1);
        __builtin_amdgcn_s_setprio(1);
#pragma unroll
        for (int m = 2; m < 4; ++m)
#pragma unroll
            for (int n = 0; n < 4; ++n)
                acc[m][n] = __builtin_amdgcn_mfma_f32_16x16x32_bf16(af[m], bf[n], acc[m][n], 0, 0, 0);
        __builtin_amdgcn_s_setprio(0);
        __builtin_amdgcn_s_barrier();
        __builtin_amdgcn_sched_barrier(0);

        if (bnd) {   // expert finished: f32 blend into total, reset per-expert acc
#pragma unroll
            for (int m = 0; m < 4; ++m)
#pragma unroll
                for (int n = 0; n < 4; ++n) {
#pragma unroll
                    for (int j = 0; j < 4; ++j)
                        accT[m][n][j] += e0[m][j] * acc[m][n][j];
                    acc[m][n] = f32x4{0.f, 0.f, 0.f, 0.f};
                }
        }

        bufR = (bufR == 2) ? 0 : bufR + 1;
        bufS = (bufS == 2) ? 0 : bufS + 1;
    }

    // epilogue: out = accT + sum_k ew*bias (bias zero in bench; exact for generality)
    float bv[4][8];
#pragma unroll
    for (int n = 0; n < 4; ++n) {
        const int gc = nbase + wcol + n * 16 + lr;
#pragma unroll
        for (int kk = 0; kk < 8; ++kk) bv[n][kk] = bias[kk * NDIM + gc];
    }
#pragma unroll
    for (int m = 0; m < 4; ++m)
#pragma unroll
        for (int j = 0; j < 4; ++j) {
            const int grow = mbase + wrow + m * 16 + lg * 4 + j;
            const float4* e4 = (const float4*)(ew + (size_t)grow * KEXP);
            const float4 ea = e4[0];
            const float4 eb = e4[1];
            const float ev[8] = {ea.x, ea.y, ea.z, ea.w, eb.x, eb.y, eb.z, eb.w};
            float* op = out + (size_t)grow * NDIM + nbase + wcol;
#pragma unroll
            for (int n = 0; n < 4; ++n) {
                float t = accT[m][n][j];
#pragma unroll
                for (int kk = 0; kk < 8; ++kk) t += ev[kk] * bv[n][kk];
                op[n * 16 + lr] = t;
            }
        }
}

// ---------------- fallback (round-1 kernel) if ws is too small --------------------
#define FLDW 40
__global__ __launch_bounds__(256, 2)
void moe_blend_gemm_fb(const float* __restrict__ x, const float* __restrict__ ew,
                       const float* __restrict__ w, const float* __restrict__ bias,
                       float* __restrict__ out) {
    __shared__ unsigned short lA[128][FLDW];
    __shared__ unsigned short lB[128][FLDW];
    const int tid = threadIdx.x, bid = blockIdx.x;
    const int nt = bid & 7, mt = bid >> 3;
    const int mbase = mt * 128, nbase = nt * 128;
    const int trow = tid >> 1, tcol = (tid & 1) * 16;
    const float* xp = x + (size_t)(mbase + trow) * INDIM + tcol;
    const float* wp = w + (size_t)(nbase + trow) * INDIM + tcol;
    const float* ep = ew + (size_t)(mbase + trow) * KEXP;
    const int wid = tid >> 6, wrB = (wid >> 1) * 64, wcB = (wid & 1) * 64;
    const int l = tid & 63, lr = l & 15, lg = l >> 4;
    f32x4 acc[4][4];
#pragma unroll
    for (int m = 0; m < 4; ++m)
#pragma unroll
        for (int n = 0; n < 4; ++n) acc[m][n] = f32x4{0.f, 0.f, 0.f, 0.f};
    const unsigned short* rdA = &lA[wrB + lr][lg * 8];
    const unsigned short* rdB = &lB[wcB + lr][lg * 8];
    unsigned int* wA = (unsigned int*)&lA[trow][tcol];
    unsigned int* wB = (unsigned int*)&lB[trow][tcol];
    float4 ra0, ra1, ra2, ra3, rb0, rb1, rb2, rb3;
    float sc;
    {
        const float4* pa = (const float4*)(xp);
        ra0 = pa[0]; ra1 = pa[1]; ra2 = pa[2]; ra3 = pa[3];
        const float4* pb = (const float4*)(wp);
        rb0 = pb[0]; rb1 = pb[1]; rb2 = pb[2]; rb3 = pb[3];
        sc = ep[0];
    }
    for (int tt = 0; tt < 256; ++tt) {
        __syncthreads();
        uint4 qa0, qa1, qb0, qb1;
        qa0.x = pack2bf(ra0.x * sc, ra0.y * sc); qa0.y = pack2bf(ra0.z * sc, ra0.w * sc);
        qa0.z = pack2bf(ra1.x * sc, ra1.y * sc); qa0.w = pack2bf(ra1.z * sc, ra1.w * sc);
        qa1.x = pack2bf(ra2.x * sc, ra2.y * sc); qa1.y = pack2bf(ra2.z * sc, ra2.w * sc);
        qa1.z = pack2bf(ra3.x * sc, ra3.y * sc); qa1.w = pack2bf(ra3.z * sc, ra3.w * sc);
        qb0.x = pack2bf(rb0.x, rb0.y); qb0.y = pack2bf(rb0.z, rb0.w);
        qb0.z = pack2bf(rb1.x, rb1.y); qb0.w = pack2bf(rb1.z, rb1.w);
        qb1.x = pack2bf(rb2.x, rb2.y); qb1.y = pack2bf(rb2.z, rb2.w);
        qb1.z = pack2bf(rb3.x, rb3.y); qb1.w = pack2bf(rb3.z, rb3.w);
        *(uint4*)(wA) = qa0; *(uint4*)(wA + 4) = qa1;
        *(uint4*)(wB) = qb0; *(uint4*)(wB + 4) = qb1;
        __syncthreads();
        if (tt + 1 < 256) {
            const int kc = (tt + 1) >> 5, i0 = ((tt + 1) & 31) * 32;
            const float4* pa = (const float4*)(xp + i0);
            ra0 = pa[0]; ra1 = pa[1]; ra2 = pa[2]; ra3 = pa[3];
            const float4* pb = (const float4*)(wp + (size_t)kc * (size_t)(NDIM * INDIM) + i0);
            rb0 = pb[0]; rb1 = pb[1]; rb2 = pb[2]; rb3 = pb[3];
            sc = ep[kc];
        }
        short8 af[4], bf[4];
#pragma unroll
        for (int m = 0; m < 4; ++m) af[m] = *(const short8*)(rdA + m * 16 * FLDW);
#pragma unroll
        for (int n = 0; n < 4; ++n) bf[n] = *(const short8*)(rdB + n * 16 * FLDW);
#pragma unroll
        for (int m = 0; m < 4; ++m)
#pragma unroll
            for (int n = 0; n < 4; ++n)
                acc[m][n] = __builtin_amdgcn_mfma_f32_16x16x32_bf16(af[m], bf[n], acc[m][n], 0, 0, 0);
    }
#pragma unroll
    for (int m = 0; m < 4; ++m)
#pragma unroll
        for (int j = 0; j < 4; ++j) {
            const int gr = mbase + wrB + m * 16 + lg * 4 + j;
            const float4* e4 = (const float4*)(ew + (size_t)gr * KEXP);
            const float4 e0 = e4[0], e1 = e4[1];
            const float eb[8] = {e0.x, e0.y, e0.z, e0.w, e1.x, e1.y, e1.z, e1.w};
            float* op = out + (size_t)gr * NDIM + nbase + wcB;
#pragma unroll
            for (int n = 0; n < 4; ++n) {
                float t = acc[m][n][j];
#pragma unroll
                for (int kk = 0; kk < 8; ++kk) t += eb[kk] * bias[kk * NDIM + nbase + wcB + n * 16 + lr];
                op[n * 16 + lr] = t;
            }
        }
}

extern "C" void kernel_launch(void* const* d_in, const int* in_sizes, int n_in,
                              void* d_out, int out_size, void* d_ws, size_t ws_size,
                              hipStream_t stream) {
    (void)in_sizes; (void)n_in; (void)out_size;
    const float* x    = (const float*)d_in[0];
    const float* ew   = (const float*)d_in[1];
    const float* w    = (const float*)d_in[2];
    const float* bias = (const float*)d_in[3];
    float* out = (float*)d_out;

    const size_t need = (size_t)(NX + NW) * sizeof(unsigned short);  // 33.5 MB
    if (ws_size >= need) {
        unsigned short* ab = (unsigned short*)d_ws;
        hipLaunchKernelGGL(convert_bf16, dim3(2048), dim3(256), 0, stream, x, w, ab);
        hipLaunchKernelGGL(moe_gemm_pipe, dim3(256), dim3(512), 0, stream, ab, ew, bias, out);
    } else {
        hipLaunchKernelGGL(moe_blend_gemm_fb, dim3(512), dim3(256), 0, stream, x, ew, w, bias, out);
    }
}

// Round 4
// 180.148 us; speedup vs baseline: 1.9355x; 1.0218x over previous
//
#include <hip/hip_runtime.h>
#include <hip/hip_bf16.h>

typedef __attribute__((ext_vector_type(8))) short short8;
typedef __attribute__((ext_vector_type(4))) float f32x4;

#define NDIM 1024
#define INDIM 1024
#define KEXP 8
#define BROWS 8192
#define NX (BROWS * INDIM)        // x elements   (8388608)
#define NW (KEXP * NDIM * INDIM)  // w elements   (8388608)

// GEMM geometry
#define BM 256
#define BN 128
#define BK 64
#define NT 128                    // K-tiles total: 8 experts * (1024/64)
#define ABUF 16384                // ushorts per A slab (2 ks * 256 rows * 32)
#define BBUF 8192                 // ushorts per B slab (2 ks * 128 rows * 32)
#define BUFU (ABUF + BBUF)        // 24576 ushorts = 48 KiB per ring slot

__device__ __forceinline__ unsigned int pack2bf(float a, float b) {
    __hip_bfloat162 h = __float22bfloat162_rn(make_float2(a, b));
    union { __hip_bfloat162 h; unsigned int u; } cv;
    cv.h = h;
    return cv.u;
}

__device__ __forceinline__ void gload16(const void* src, void* ldsdst) {
    __builtin_amdgcn_global_load_lds(
        (__attribute__((address_space(1))) void*)(src),
        (__attribute__((address_space(3))) void*)(ldsdst), 16, 0, 0);
}

// ---------------- kernel 1: f32 -> bf16 convert of x and W into ws ----------------
__global__ void convert_bf16(const float* __restrict__ x, const float* __restrict__ w,
                             unsigned short* __restrict__ dst) {
    const long total = (long)NX + NW;
    const long stride = (long)gridDim.x * blockDim.x * 8;
    for (long i = ((long)blockIdx.x * blockDim.x + threadIdx.x) * 8; i < total; i += stride) {
        const float* s = (i < NX) ? (x + i) : (w + (i - NX));
        float4 a = ((const float4*)s)[0];
        float4 b = ((const float4*)s)[1];
        uint4 q;
        q.x = pack2bf(a.x, a.y); q.y = pack2bf(a.z, a.w);
        q.z = pack2bf(b.x, b.y); q.w = pack2bf(b.z, b.w);
        *(uint4*)(dst + i) = q;
    }
}

// ------- kernel 2: ring-3 counted-vmcnt, 1-barrier/tile, reg-ping-pong GEMM -------
// 256x128 tile, BK=64, 8 waves (4M x 2N, wave tile 64x64), per-expert f32 blend.
__global__ __launch_bounds__(512, 2)
void moe_gemm_pipe(const unsigned short* __restrict__ ab,   // bf16: x at 0, w at NX
                   const float* __restrict__ ew,
                   const float* __restrict__ bias,
                   float* __restrict__ out) {
    __shared__ __align__(16) unsigned short lds[3 * BUFU];   // 144 KiB ring

    const int tid = threadIdx.x;
    const int bid = blockIdx.x;
    const int nt = bid & 7;            // n-tile == XCD: B panel (2 MB) stays L2-resident
    const int mt = bid >> 3;           // 0..31
    const int mbase = mt * BM;
    const int nbase = nt * BN;

    const int w  = tid >> 6;           // wave 0..7
    const int l  = tid & 63;
    const int lr = l & 15;
    const int lg = l >> 4;
    const int wrow = (w >> 1) * 64;    // 4 M-groups
    const int wcol = (w & 1) * 64;     // 2 N-groups

    // staging lane coords: chunk = 16 rows x 32 cols bf16 = 1024 B
    const int lrow = l >> 2;                     // row within chunk
    const int sg = (l & 3) ^ ((l >> 3) & 3);     // pre-swizzled 8-elem col block

    const unsigned short* Xb = ab;
    const unsigned short* Wb = ab + NX;

    // fragment read offsets (ushort units) with matching XOR involution
    const int swz = (lr >> 1) & 3;
    int aoff[4][2], boff[4][2];
#pragma unroll
    for (int m = 0; m < 4; ++m)
#pragma unroll
        for (int ks = 0; ks < 2; ++ks)
            aoff[m][ks] = ks * 8192 + (wrow + m * 16 + lr) * 32 + ((lg ^ swz) * 8);
#pragma unroll
    for (int n = 0; n < 4; ++n)
#pragma unroll
        for (int ks = 0; ks < 2; ++ks)
            boff[n][ks] = ABUF + ks * 4096 + (wcol + n * 16 + lr) * 32 + ((lg ^ swz) * 8);

    // stage helpers: wave-uniform LDS dest (global_load_lds scatters lane*16)
    auto stageA = [&](int buf, int kt, int i) {
        const int c = i * 8 + w;                  // 0..31
        const int ks = c >> 4, rg = c & 15;
        const unsigned short* src = Xb + (size_t)(mbase + rg * 16 + lrow) * INDIM
                                  + (size_t)((kt & 15) * 64 + ks * 32 + sg * 8);
        gload16(src, &lds[buf * BUFU + c * 512]);
    };
    auto stageB = [&](int buf, int kt, int i) {
        const int c = i * 8 + w;                  // 0..15
        const int ks = c >> 3, rg = c & 7;
        const unsigned short* src = Wb + (size_t)(kt >> 4) * (NDIM * INDIM)
                                  + (size_t)(nbase + rg * 16 + lrow) * INDIM
                                  + (size_t)((kt & 15) * 64 + ks * 32 + sg * 8);
        gload16(src, &lds[buf * BUFU + ABUF + c * 512]);
    };

    f32x4 acc[4][4], accT[4][4];
#pragma unroll
    for (int m = 0; m < 4; ++m)
#pragma unroll
        for (int n = 0; n < 4; ++n) {
            acc[m][n] = f32x4{0.f, 0.f, 0.f, 0.f};
            accT[m][n] = f32x4{0.f, 0.f, 0.f, 0.f};
        }

    // prologue: stage tiles 0,1 (6 vmem per wave each, in order)
#pragma unroll
    for (int t = 0; t < 2; ++t) {
        stageA(t, t, 0); stageA(t, t, 1); stageA(t, t, 2); stageA(t, t, 3);
        stageB(t, t, 0); stageB(t, t, 1);
    }

    int bufR = 0, bufS = 2;
#pragma unroll 1
    for (int kt = 0; kt < NT; ++kt) {
        const bool doS = (kt + 2) < NT;
        const bool bnd = (kt & 15) == 15;

        // tile gate: own stage(kt) landed (vmcnt<=6 leaves stage(kt+1) in flight),
        // then barrier makes every wave's staging visible. NEVER vmcnt(0) mid-loop.
        if (kt < NT - 2)
            asm volatile("s_waitcnt vmcnt(6)\n\ts_barrier" ::: "memory");
        else
            asm volatile("s_waitcnt vmcnt(0)\n\ts_barrier" ::: "memory");

        // blend weights issued EARLY (before stage issues) so their vmcnt wait at
        // blend time does not drain the staging queue; latency hides under MFMA.
        float e0[4][4];
        if (bnd) {
            const int eidx = kt >> 4;
#pragma unroll
            for (int m = 0; m < 4; ++m)
#pragma unroll
                for (int j = 0; j < 4; ++j)
                    e0[m][j] = ew[(size_t)(mbase + wrow + m * 16 + lg * 4 + j) * KEXP + eidx];
        }

        const unsigned short* lb = &lds[bufR * BUFU];
        short8 a0[4], b0[4], a1[4], b1[4];

        // issue ks0 fragment reads (8 ds_read_b128)
#pragma unroll
        for (int m = 0; m < 4; ++m) a0[m] = *(const short8*)(lb + aoff[m][0]);
#pragma unroll
        for (int n = 0; n < 4; ++n) b0[n] = *(const short8*)(lb + boff[n][0]);

        // issue next-next tile staging (6 global_load_lds on VMEM pipe)
        if (doS) {
            stageA(bufS, kt + 2, 0); stageA(bufS, kt + 2, 1);
            stageA(bufS, kt + 2, 2); stageA(bufS, kt + 2, 3);
            stageB(bufS, kt + 2, 0); stageB(bufS, kt + 2, 1);
        }

        // issue ks1 fragment reads (8 ds_read_b128) — drain under cluster-0 MFMA
#pragma unroll
        for (int m = 0; m < 4; ++m) a1[m] = *(const short8*)(lb + aoff[m][1]);
#pragma unroll
        for (int n = 0; n < 4; ++n) b1[n] = *(const short8*)(lb + boff[n][1]);

        // cluster 0: compiler waits lgkmcnt(8) (only ks0 reads), ks1 still in flight
        __builtin_amdgcn_s_setprio(1);
#pragma unroll
        for (int m = 0; m < 4; ++m)
#pragma unroll
            for (int n = 0; n < 4; ++n)
                acc[m][n] = __builtin_amdgcn_mfma_f32_16x16x32_bf16(a0[m], b0[n], acc[m][n], 0, 0, 0);
        __builtin_amdgcn_s_setprio(0);

        // cluster 1: lgkmcnt(0)
        __builtin_amdgcn_s_setprio(1);
#pragma unroll
        for (int m = 0; m < 4; ++m)
#pragma unroll
            for (int n = 0; n < 4; ++n)
                acc[m][n] = __builtin_amdgcn_mfma_f32_16x16x32_bf16(a1[m], b1[n], acc[m][n], 0, 0, 0);
        __builtin_amdgcn_s_setprio(0);

        if (bnd) {   // expert finished: f32 blend into total, reset per-expert acc
#pragma unroll
            for (int m = 0; m < 4; ++m)
#pragma unroll
                for (int n = 0; n < 4; ++n) {
#pragma unroll
                    for (int j = 0; j < 4; ++j)
                        accT[m][n][j] += e0[m][j] * acc[m][n][j];
                    acc[m][n] = f32x4{0.f, 0.f, 0.f, 0.f};
                }
        }

        bufR = (bufR == 2) ? 0 : bufR + 1;
        bufS = (bufS == 2) ? 0 : bufS + 1;
    }

    // epilogue: out = accT + sum_k ew*bias (bias zero in bench; exact for generality)
    float bv[4][8];
#pragma unroll
    for (int n = 0; n < 4; ++n) {
        const int gc = nbase + wcol + n * 16 + lr;
#pragma unroll
        for (int kk = 0; kk < 8; ++kk) bv[n][kk] = bias[kk * NDIM + gc];
    }
#pragma unroll
    for (int m = 0; m < 4; ++m)
#pragma unroll
        for (int j = 0; j < 4; ++j) {
            const int grow = mbase + wrow + m * 16 + lg * 4 + j;
            const float4* e4 = (const float4*)(ew + (size_t)grow * KEXP);
            const float4 ea = e4[0];
            const float4 eb = e4[1];
            const float ev[8] = {ea.x, ea.y, ea.z, ea.w, eb.x, eb.y, eb.z, eb.w};
            float* op = out + (size_t)grow * NDIM + nbase + wcol;
#pragma unroll
            for (int n = 0; n < 4; ++n) {
                float t = accT[m][n][j];
#pragma unroll
                for (int kk = 0; kk < 8; ++kk) t += ev[kk] * bv[n][kk];
                op[n * 16 + lr] = t;
            }
        }
}

// ---------------- fallback (round-1 kernel) if ws is too small --------------------
#define FLDW 40
__global__ __launch_bounds__(256, 2)
void moe_blend_gemm_fb(const float* __restrict__ x, const float* __restrict__ ew,
                       const float* __restrict__ w, const float* __restrict__ bias,
                       float* __restrict__ out) {
    __shared__ unsigned short lA[128][FLDW];
    __shared__ unsigned short lB[128][FLDW];
    const int tid = threadIdx.x, bid = blockIdx.x;
    const int nt = bid & 7, mt = bid >> 3;
    const int mbase = mt * 128, nbase = nt * 128;
    const int trow = tid >> 1, tcol = (tid & 1) * 16;
    const float* xp = x + (size_t)(mbase + trow) * INDIM + tcol;
    const float* wp = w + (size_t)(nbase + trow) * INDIM + tcol;
    const float* ep = ew + (size_t)(mbase + trow) * KEXP;
    const int wid = tid >> 6, wrB = (wid >> 1) * 64, wcB = (wid & 1) * 64;
    const int l = tid & 63, lr = l & 15, lg = l >> 4;
    f32x4 acc[4][4];
#pragma unroll
    for (int m = 0; m < 4; ++m)
#pragma unroll
        for (int n = 0; n < 4; ++n) acc[m][n] = f32x4{0.f, 0.f, 0.f, 0.f};
    const unsigned short* rdA = &lA[wrB + lr][lg * 8];
    const unsigned short* rdB = &lB[wcB + lr][lg * 8];
    unsigned int* wA = (unsigned int*)&lA[trow][tcol];
    unsigned int* wB = (unsigned int*)&lB[trow][tcol];
    float4 ra0, ra1, ra2, ra3, rb0, rb1, rb2, rb3;
    float sc;
    {
        const float4* pa = (const float4*)(xp);
        ra0 = pa[0]; ra1 = pa[1]; ra2 = pa[2]; ra3 = pa[3];
        const float4* pb = (const float4*)(wp);
        rb0 = pb[0]; rb1 = pb[1]; rb2 = pb[2]; rb3 = pb[3];
        sc = ep[0];
    }
    for (int tt = 0; tt < 256; ++tt) {
        __syncthreads();
        uint4 qa0, qa1, qb0, qb1;
        qa0.x = pack2bf(ra0.x * sc, ra0.y * sc); qa0.y = pack2bf(ra0.z * sc, ra0.w * sc);
        qa0.z = pack2bf(ra1.x * sc, ra1.y * sc); qa0.w = pack2bf(ra1.z * sc, ra1.w * sc);
        qa1.x = pack2bf(ra2.x * sc, ra2.y * sc); qa1.y = pack2bf(ra2.z * sc, ra2.w * sc);
        qa1.z = pack2bf(ra3.x * sc, ra3.y * sc); qa1.w = pack2bf(ra3.z * sc, ra3.w * sc);
        qb0.x = pack2bf(rb0.x, rb0.y); qb0.y = pack2bf(rb0.z, rb0.w);
        qb0.z = pack2bf(rb1.x, rb1.y); qb0.w = pack2bf(rb1.z, rb1.w);
        qb1.x = pack2bf(rb2.x, rb2.y); qb1.y = pack2bf(rb2.z, rb2.w);
        qb1.z = pack2bf(rb3.x, rb3.y); qb1.w = pack2bf(rb3.z, rb3.w);
        *(uint4*)(wA) = qa0; *(uint4*)(wA + 4) = qa1;
        *(uint4*)(wB) = qb0; *(uint4*)(wB + 4) = qb1;
        __syncthreads();
        if (tt + 1 < 256) {
            const int kc = (tt + 1) >> 5, i0 = ((tt + 1) & 31) * 32;
            const float4* pa = (const float4*)(xp + i0);
            ra0 = pa[0]; ra1 = pa[1]; ra2 = pa[2]; ra3 = pa[3];
            const float4* pb = (const float4*)(wp + (size_t)kc * (size_t)(NDIM * INDIM) + i0);
            rb0 = pb[0]; rb1 = pb[1]; rb2 = pb[2]; rb3 = pb[3];
            sc = ep[kc];
        }
        short8 af[4], bf[4];
#pragma unroll
        for (int m = 0; m < 4; ++m) af[m] = *(const short8*)(rdA + m * 16 * FLDW);
#pragma unroll
        for (int n = 0; n < 4; ++n) bf[n] = *(const short8*)(rdB + n * 16 * FLDW);
#pragma unroll
        for (int m = 0; m < 4; ++m)
#pragma unroll
            for (int n = 0; n < 4; ++n)
                acc[m][n] = __builtin_amdgcn_mfma_f32_16x16x32_bf16(af[m], bf[n], acc[m][n], 0, 0, 0);
    }
#pragma unroll
    for (int m = 0; m < 4; ++m)
#pragma unroll
        for (int j = 0; j < 4; ++j) {
            const int gr = mbase + wrB + m * 16 + lg * 4 + j;
            const float4* e4 = (const float4*)(ew + (size_t)gr * KEXP);
            const float4 e0 = e4[0], e1 = e4[1];
            const float eb[8] = {e0.x, e0.y, e0.z, e0.w, e1.x, e1.y, e1.z, e1.w};
            float* op = out + (size_t)gr * NDIM + nbase + wcB;
#pragma unroll
            for (int n = 0; n < 4; ++n) {
                float t = acc[m][n][j];
#pragma unroll
                for (int kk = 0; kk < 8; ++kk) t += eb[kk] * bias[kk * NDIM + nbase + wcB + n * 16 + lr];
                op[n * 16 + lr] = t;
            }
        }
}

extern "C" void kernel_launch(void* const* d_in, const int* in_sizes, int n_in,
                              void* d_out, int out_size, void* d_ws, size_t ws_size,
                              hipStream_t stream) {
    (void)in_sizes; (void)n_in; (void)out_size;
    const float* x    = (const float*)d_in[0];
    const float* ew   = (const float*)d_in[1];
    const float* w    = (const float*)d_in[2];
    const float* bias = (const float*)d_in[3];
    float* out = (float*)d_out;

    const size_t need = (size_t)(NX + NW) * sizeof(unsigned short);  // 33.5 MB
    if (ws_size >= need) {
        unsigned short* ab = (unsigned short*)d_ws;
        hipLaunchKernelGGL(convert_bf16, dim3(2048), dim3(256), 0, stream, x, w, ab);
        hipLaunchKernelGGL(moe_gemm_pipe, dim3(256), dim3(512), 0, stream, ab, ew, bias, out);
    } else {
        hipLaunchKernelGGL(moe_blend_gemm_fb, dim3(512), dim3(256), 0, stream, x, ew, w, bias, out);
    }
}

// Round 5
// 167.802 us; speedup vs baseline: 2.0779x; 1.0736x over previous
//
#include <hip/hip_runtime.h>
#include <hip/hip_bf16.h>

typedef __attribute__((ext_vector_type(8))) short short8;
typedef __attribute__((ext_vector_type(4))) float f32x4;

#define NDIM 1024
#define INDIM 1024
#define KEXP 8
#define BROWS 8192
#define NX (BROWS * INDIM)        // x elements        8388608
#define NW (KEXP * NDIM * INDIM)  // w elements        8388608
#define NA (BROWS * KEXP * INDIM) // A' elements      67108864
#define NPH (BROWS * NDIM)        // partial elems     8388608

__device__ __forceinline__ unsigned int pack2bf(float a, float b) {
    __hip_bfloat162 h = __float22bfloat162_rn(make_float2(a, b));
    union { __hip_bfloat162 h; unsigned int u; } cv;
    cv.h = h;
    return cv.u;
}

__device__ __forceinline__ float bf2f(unsigned short u) {
    return __uint_as_float(((unsigned int)u) << 16);
}

__device__ __forceinline__ void gload16(const void* src, void* ldsdst) {
    __builtin_amdgcn_global_load_lds(
        (__attribute__((address_space(1))) void*)(src),
        (__attribute__((address_space(3))) void*)(ldsdst), 16, 0, 0);
}

// ============ path A kernels (needs ws >= 184.5 MB) ============

// A'[b][k*1024+i] = bf16(ew[b,k] * x[b,i])   — folds routing weights into A
__global__ void convert_a(const float* __restrict__ x, const float* __restrict__ ew,
                          unsigned short* __restrict__ Ap) {
    const int t = blockIdx.x * blockDim.x + threadIdx.x;
    if (t >= (BROWS * INDIM / 8)) return;
    const int b = t >> 7;
    const int i0 = (t & 127) * 8;
    const float4 xa = *(const float4*)(x + (size_t)b * INDIM + i0);
    const float4 xb = *(const float4*)(x + (size_t)b * INDIM + i0 + 4);
    const float4 ea = *(const float4*)(ew + (size_t)b * KEXP);
    const float4 e2 = *(const float4*)(ew + (size_t)b * KEXP + 4);
    const float e[8] = {ea.x, ea.y, ea.z, ea.w, e2.x, e2.y, e2.z, e2.w};
    unsigned short* dst = Ap + (size_t)b * (KEXP * INDIM) + i0;
#pragma unroll
    for (int k = 0; k < 8; ++k) {
        const float s = e[k];
        uint4 q;
        q.x = pack2bf(xa.x * s, xa.y * s);
        q.y = pack2bf(xa.z * s, xa.w * s);
        q.z = pack2bf(xb.x * s, xb.y * s);
        q.w = pack2bf(xb.z * s, xb.w * s);
        *(uint4*)(dst + (size_t)k * INDIM) = q;
    }
}

__global__ void convert_w(const float* __restrict__ w, unsigned short* __restrict__ Wp) {
    const long i = ((long)blockIdx.x * blockDim.x + threadIdx.x) * 8;
    if (i >= NW) return;
    const float4 a = ((const float4*)(w + i))[0];
    const float4 b = ((const float4*)(w + i))[1];
    uint4 q;
    q.x = pack2bf(a.x, a.y); q.y = pack2bf(a.z, a.w);
    q.z = pack2bf(b.x, b.y); q.w = pack2bf(b.z, b.w);
    *(uint4*)(Wp + i) = q;
}

// pure bf16 GEMM, K split in 2 expert-aligned halves. BM=BN=256, BK=64,
// 8 waves of 128x64, single acc (128 VGPR), dbuf-2 LDS (128 KiB),
// one vmcnt(0)+barrier gate per tile, quadrant-pipelined fragment reads.
__global__ __launch_bounds__(512, 2)
void moe_gemm_ks(const unsigned short* __restrict__ Ap,   // [8192][8192]
                 const unsigned short* __restrict__ Wp,   // [8][1024][1024]
                 unsigned short* __restrict__ Pp) {       // [2][8192][1024] partials
    __shared__ __align__(16) unsigned short lds[2 * 32768];   // 128 KiB

    const int tid = threadIdx.x;
    const int bid = blockIdx.x;
    const int comp = bid & 7;          // (nt,h) == XCD: W panel (2 MB) L2-pinned
    const int nt = comp >> 1;          // 0..3
    const int h  = comp & 1;           // K half (experts 0-3 / 4-7)
    const int mt = bid >> 3;           // 0..31
    const int mbase = mt * 256;
    const int nbase = nt * 256;
    const int kofs = h * 4096;

    const int w  = tid >> 6;           // wave 0..7 (2M x 4N)
    const int l  = tid & 63;
    const int lr = l & 15;
    const int lg = l >> 4;
    const int wrow = (w >> 2) * 128;
    const int wcol = (w & 3) * 64;

    // staging lane coords: chunk = 16 rows x 32 cols bf16 = 1024 B
    const int lrow = l >> 2;
    const int sg = (l & 3) ^ ((l >> 3) & 3);     // pre-swizzled col block (involution)
    const int swz = (lr >> 1) & 3;

    // fragment read offsets (ushort units), matching XOR involution
    int aoff[8][2], boff[4][2];
#pragma unroll
    for (int mf = 0; mf < 8; ++mf)
#pragma unroll
        for (int ks = 0; ks < 2; ++ks)
            aoff[mf][ks] = ks * 8192 + (wrow + mf * 16 + lr) * 32 + ((lg ^ swz) * 8);
#pragma unroll
    for (int nf = 0; nf < 4; ++nf)
#pragma unroll
        for (int ks = 0; ks < 2; ++ks)
            boff[nf][ks] = 16384 + ks * 8192 + (wcol + nf * 16 + lr) * 32 + ((lg ^ swz) * 8);

    // staging: 64 chunks/tile (A ids 0-31, B ids 32-63), wave w owns ids w*8..w*8+7
    auto stage4 = [&](int slot, int kt, int half) {
#pragma unroll
        for (int i = 0; i < 4; ++i) {
            const int id = w * 8 + half * 4 + i;
            unsigned short* dst = &lds[slot * 32768 + id * 512];
            const int ks = (id >> 4) & 1;
            const int sub = id & 15;
            const int kcb = kofs + kt * 64 + ks * 32 + sg * 8;
            if (id < 32) {
                gload16(Ap + (size_t)(mbase + sub * 16 + lrow) * (KEXP * INDIM) + kcb, dst);
            } else {
                gload16(Wp + (size_t)(kcb >> 10) * (NDIM * INDIM)
                           + (size_t)(nbase + sub * 16 + lrow) * INDIM + (kcb & 1023), dst);
            }
        }
    };

    f32x4 acc[8][4];
#pragma unroll
    for (int mf = 0; mf < 8; ++mf)
#pragma unroll
        for (int nf = 0; nf < 4; ++nf) acc[mf][nf] = f32x4{0.f, 0.f, 0.f, 0.f};

    stage4(0, 0, 0);
    stage4(0, 0, 1);

#pragma unroll 1
    for (int kt = 0; kt < 64; ++kt) {
        const int cs = kt & 1;
        const bool doS = (kt + 1) < 64;

        // tile gate: own stage(kt) landed; barrier publishes all waves' staging.
        // drain is cheap: these loads were issued a full tile (~2500 cy) ago.
        asm volatile("s_waitcnt vmcnt(0)\n\ts_barrier" ::: "memory");

        const unsigned short* lb = &lds[cs * 32768];
        short8 alo[4], ahi[4], b0[4], b1[4];

        // q0 operands + first staging batch + q1 A-frags (drain under q0 MFMA)
#pragma unroll
        for (int m = 0; m < 4; ++m) alo[m] = *(const short8*)(lb + aoff[m][0]);
#pragma unroll
        for (int n = 0; n < 4; ++n) b0[n] = *(const short8*)(lb + boff[n][0]);
        if (doS) stage4(cs ^ 1, kt + 1, 0);
#pragma unroll
        for (int m = 0; m < 4; ++m) ahi[m] = *(const short8*)(lb + aoff[4 + m][0]);

        __builtin_amdgcn_s_setprio(1);
#pragma unroll
        for (int m = 0; m < 4; ++m)
#pragma unroll
            for (int n = 0; n < 4; ++n)
                acc[m][n] = __builtin_amdgcn_mfma_f32_16x16x32_bf16(alo[m], b0[n], acc[m][n], 0, 0, 0);
        __builtin_amdgcn_s_setprio(0);

        // q2 operands (ks1) issued now; second staging batch
#pragma unroll
        for (int n = 0; n < 4; ++n) b1[n] = *(const short8*)(lb + boff[n][1]);
#pragma unroll
        for (int m = 0; m < 4; ++m) alo[m] = *(const short8*)(lb + aoff[m][1]);
        if (doS) stage4(cs ^ 1, kt + 1, 1);

        __builtin_amdgcn_s_setprio(1);
#pragma unroll
        for (int m = 0; m < 4; ++m)
#pragma unroll
            for (int n = 0; n < 4; ++n)
                acc[4 + m][n] = __builtin_amdgcn_mfma_f32_16x16x32_bf16(ahi[m], b0[n], acc[4 + m][n], 0, 0, 0);
        __builtin_amdgcn_s_setprio(0);

#pragma unroll
        for (int m = 0; m < 4; ++m) ahi[m] = *(const short8*)(lb + aoff[4 + m][1]);

        __builtin_amdgcn_s_setprio(1);
#pragma unroll
        for (int m = 0; m < 4; ++m)
#pragma unroll
            for (int n = 0; n < 4; ++n)
                acc[m][n] = __builtin_amdgcn_mfma_f32_16x16x32_bf16(alo[m], b1[n], acc[m][n], 0, 0, 0);
        __builtin_amdgcn_s_setprio(0);

        __builtin_amdgcn_s_setprio(1);
#pragma unroll
        for (int m = 0; m < 4; ++m)
#pragma unroll
            for (int n = 0; n < 4; ++n)
                acc[4 + m][n] = __builtin_amdgcn_mfma_f32_16x16x32_bf16(ahi[m], b1[n], acc[4 + m][n], 0, 0, 0);
        __builtin_amdgcn_s_setprio(0);
    }

    // epilogue: bf16 partial store
#pragma unroll
    for (int mf = 0; mf < 8; ++mf)
#pragma unroll
        for (int j = 0; j < 4; ++j) {
            const int grow = mbase + wrow + mf * 16 + lg * 4 + j;
            unsigned short* op = Pp + (size_t)h * NPH + (size_t)grow * NDIM + nbase + wcol;
#pragma unroll
            for (int nf = 0; nf < 4; ++nf) {
                union { __hip_bfloat16 hh; unsigned short u; } cv;
                cv.hh = __float2bfloat16(acc[mf][nf][j]);
                op[nf * 16 + lr] = cv.u;
            }
        }
}

// out = P0 + P1 + ew @ bias   (exact f32 blend of the two K-halves + bias)
__global__ void reduce_blend(const unsigned short* __restrict__ Pp,
                             const float* __restrict__ ew,
                             const float* __restrict__ bias,
                             float* __restrict__ out) {
    const long base = ((long)blockIdx.x * blockDim.x + threadIdx.x) * 8;
    if (base >= NPH) return;
    const int b = (int)(base >> 10);
    const int o = (int)(base & 1023);
    const short8 p0 = *(const short8*)(Pp + base);
    const short8 p1 = *(const short8*)(Pp + NPH + base);
    const float4 ea = *(const float4*)(ew + (size_t)b * KEXP);
    const float4 e2 = *(const float4*)(ew + (size_t)b * KEXP + 4);
    const float e[8] = {ea.x, ea.y, ea.z, ea.w, e2.x, e2.y, e2.z, e2.w};
    float r[8];
#pragma unroll
    for (int j = 0; j < 8; ++j)
        r[j] = bf2f((unsigned short)p0[j]) + bf2f((unsigned short)p1[j]);
#pragma unroll
    for (int k = 0; k < 8; ++k)
#pragma unroll
        for (int j = 0; j < 8; ++j) r[j] += e[k] * bias[k * NDIM + o + j];
    *(float4*)(out + base) = make_float4(r[0], r[1], r[2], r[3]);
    *(float4*)(out + base + 4) = make_float4(r[4], r[5], r[6], r[7]);
}

// ============ path B: round-4 pipeline (needs ws >= 33.5 MB) ============

#define BM 256
#define BN 128
#define BK 64
#define NT 128
#define ABUF 16384
#define BBUF 8192
#define BUFU (ABUF + BBUF)

__global__ void convert_bf16(const float* __restrict__ x, const float* __restrict__ w,
                             unsigned short* __restrict__ dst) {
    const long total = (long)NX + NW;
    const long stride = (long)gridDim.x * blockDim.x * 8;
    for (long i = ((long)blockIdx.x * blockDim.x + threadIdx.x) * 8; i < total; i += stride) {
        const float* s = (i < NX) ? (x + i) : (w + (i - NX));
        float4 a = ((const float4*)s)[0];
        float4 b = ((const float4*)s)[1];
        uint4 q;
        q.x = pack2bf(a.x, a.y); q.y = pack2bf(a.z, a.w);
        q.z = pack2bf(b.x, b.y); q.w = pack2bf(b.z, b.w);
        *(uint4*)(dst + i) = q;
    }
}

__global__ __launch_bounds__(512, 2)
void moe_gemm_pipe(const unsigned short* __restrict__ ab,
                   const float* __restrict__ ew,
                   const float* __restrict__ bias,
                   float* __restrict__ out) {
    __shared__ __align__(16) unsigned short lds[3 * BUFU];

    const int tid = threadIdx.x;
    const int bid = blockIdx.x;
    const int nt = bid & 7;
    const int mt = bid >> 3;
    const int mbase = mt * BM;
    const int nbase = nt * BN;

    const int w  = tid >> 6;
    const int l  = tid & 63;
    const int lr = l & 15;
    const int lg = l >> 4;
    const int wrow = (w >> 1) * 64;
    const int wcol = (w & 1) * 64;

    const int lrow = l >> 2;
    const int sg = (l & 3) ^ ((l >> 3) & 3);

    const unsigned short* Xb = ab;
    const unsigned short* Wb = ab + NX;

    const int swz = (lr >> 1) & 3;
    int aoff[4][2], boff[4][2];
#pragma unroll
    for (int m = 0; m < 4; ++m)
#pragma unroll
        for (int ks = 0; ks < 2; ++ks)
            aoff[m][ks] = ks * 8192 + (wrow + m * 16 + lr) * 32 + ((lg ^ swz) * 8);
#pragma unroll
    for (int n = 0; n < 4; ++n)
#pragma unroll
        for (int ks = 0; ks < 2; ++ks)
            boff[n][ks] = ABUF + ks * 4096 + (wcol + n * 16 + lr) * 32 + ((lg ^ swz) * 8);

    auto stageA = [&](int buf, int kt, int i) {
        const int c = i * 8 + w;
        const int ks = c >> 4, rg = c & 15;
        const unsigned short* src = Xb + (size_t)(mbase + rg * 16 + lrow) * INDIM
                                  + (size_t)((kt & 15) * 64 + ks * 32 + sg * 8);
        gload16(src, &lds[buf * BUFU + c * 512]);
    };
    auto stageB = [&](int buf, int kt, int i) {
        const int c = i * 8 + w;
        const int ks = c >> 3, rg = c & 7;
        const unsigned short* src = Wb + (size_t)(kt >> 4) * (NDIM * INDIM)
                                  + (size_t)(nbase + rg * 16 + lrow) * INDIM
                                  + (size_t)((kt & 15) * 64 + ks * 32 + sg * 8);
        gload16(src, &lds[buf * BUFU + ABUF + c * 512]);
    };

    f32x4 acc[4][4], accT[4][4];
#pragma unroll
    for (int m = 0; m < 4; ++m)
#pragma unroll
        for (int n = 0; n < 4; ++n) {
            acc[m][n] = f32x4{0.f, 0.f, 0.f, 0.f};
            accT[m][n] = f32x4{0.f, 0.f, 0.f, 0.f};
        }

#pragma unroll
    for (int t = 0; t < 2; ++t) {
        stageA(t, t, 0); stageA(t, t, 1); stageA(t, t, 2); stageA(t, t, 3);
        stageB(t, t, 0); stageB(t, t, 1);
    }

    int bufR = 0, bufS = 2;
#pragma unroll 1
    for (int kt = 0; kt < NT; ++kt) {
        const bool doS = (kt + 2) < NT;
        const bool bnd = (kt & 15) == 15;

        if (kt < NT - 2)
            asm volatile("s_waitcnt vmcnt(6)\n\ts_barrier" ::: "memory");
        else
            asm volatile("s_waitcnt vmcnt(0)\n\ts_barrier" ::: "memory");

        float e0[4][4];
        if (bnd) {
            const int eidx = kt >> 4;
#pragma unroll
            for (int m = 0; m < 4; ++m)
#pragma unroll
                for (int j = 0; j < 4; ++j)
                    e0[m][j] = ew[(size_t)(mbase + wrow + m * 16 + lg * 4 + j) * KEXP + eidx];
        }

        const unsigned short* lb = &lds[bufR * BUFU];
        short8 a0[4], b0[4], a1[4], b1[4];
#pragma unroll
        for (int m = 0; m < 4; ++m) a0[m] = *(const short8*)(lb + aoff[m][0]);
#pragma unroll
        for (int n = 0; n < 4; ++n) b0[n] = *(const short8*)(lb + boff[n][0]);
        if (doS) {
            stageA(bufS, kt + 2, 0); stageA(bufS, kt + 2, 1);
            stageA(bufS, kt + 2, 2); stageA(bufS, kt + 2, 3);
            stageB(bufS, kt + 2, 0); stageB(bufS, kt + 2, 1);
        }
#pragma unroll
        for (int m = 0; m < 4; ++m) a1[m] = *(const short8*)(lb + aoff[m][1]);
#pragma unroll
        for (int n = 0; n < 4; ++n) b1[n] = *(const short8*)(lb + boff[n][1]);

        __builtin_amdgcn_s_setprio(1);
#pragma unroll
        for (int m = 0; m < 4; ++m)
#pragma unroll
            for (int n = 0; n < 4; ++n)
                acc[m][n] = __builtin_amdgcn_mfma_f32_16x16x32_bf16(a0[m], b0[n], acc[m][n], 0, 0, 0);
        __builtin_amdgcn_s_setprio(0);
        __builtin_amdgcn_s_setprio(1);
#pragma unroll
        for (int m = 0; m < 4; ++m)
#pragma unroll
            for (int n = 0; n < 4; ++n)
                acc[m][n] = __builtin_amdgcn_mfma_f32_16x16x32_bf16(a1[m], b1[n], acc[m][n], 0, 0, 0);
        __builtin_amdgcn_s_setprio(0);

        if (bnd) {
#pragma unroll
            for (int m = 0; m < 4; ++m)
#pragma unroll
                for (int n = 0; n < 4; ++n) {
#pragma unroll
                    for (int j = 0; j < 4; ++j)
                        accT[m][n][j] += e0[m][j] * acc[m][n][j];
                    acc[m][n] = f32x4{0.f, 0.f, 0.f, 0.f};
                }
        }

        bufR = (bufR == 2) ? 0 : bufR + 1;
        bufS = (bufS == 2) ? 0 : bufS + 1;
    }

    float bv[4][8];
#pragma unroll
    for (int n = 0; n < 4; ++n) {
        const int gc = nbase + wcol + n * 16 + lr;
#pragma unroll
        for (int kk = 0; kk < 8; ++kk) bv[n][kk] = bias[kk * NDIM + gc];
    }
#pragma unroll
    for (int m = 0; m < 4; ++m)
#pragma unroll
        for (int j = 0; j < 4; ++j) {
            const int grow = mbase + wrow + m * 16 + lg * 4 + j;
            const float4* e4 = (const float4*)(ew + (size_t)grow * KEXP);
            const float4 ea = e4[0];
            const float4 eb = e4[1];
            const float ev[8] = {ea.x, ea.y, ea.z, ea.w, eb.x, eb.y, eb.z, eb.w};
            float* op = out + (size_t)grow * NDIM + nbase + wcol;
#pragma unroll
            for (int n = 0; n < 4; ++n) {
                float t = accT[m][n][j];
#pragma unroll
                for (int kk = 0; kk < 8; ++kk) t += ev[kk] * bv[n][kk];
                op[n * 16 + lr] = t;
            }
        }
}

extern "C" void kernel_launch(void* const* d_in, const int* in_sizes, int n_in,
                              void* d_out, int out_size, void* d_ws, size_t ws_size,
                              hipStream_t stream) {
    (void)in_sizes; (void)n_in; (void)out_size;
    const float* x    = (const float*)d_in[0];
    const float* ew   = (const float*)d_in[1];
    const float* w    = (const float*)d_in[2];
    const float* bias = (const float*)d_in[3];
    float* out = (float*)d_out;

    const size_t needA = ((size_t)NA + NW + 2 * (size_t)NPH) * sizeof(unsigned short); // 184.5 MB
    const size_t needB = (size_t)(NX + NW) * sizeof(unsigned short);                   // 33.5 MB

    if (ws_size >= needA) {
        unsigned short* Ap = (unsigned short*)d_ws;
        unsigned short* Wp = Ap + NA;
        unsigned short* Pp = Wp + NW;
        hipLaunchKernelGGL(convert_a, dim3(4096), dim3(256), 0, stream, x, ew, Ap);
        hipLaunchKernelGGL(convert_w, dim3(4096), dim3(256), 0, stream, w, Wp);
        hipLaunchKernelGGL(moe_gemm_ks, dim3(256), dim3(512), 0, stream, Ap, Wp, Pp);
        hipLaunchKernelGGL(reduce_blend, dim3(4096), dim3(256), 0, stream, Pp, ew, bias, out);
    } else if (ws_size >= needB) {
        unsigned short* ab = (unsigned short*)d_ws;
        hipLaunchKernelGGL(convert_bf16, dim3(2048), dim3(256), 0, stream, x, w, ab);
        hipLaunchKernelGGL(moe_gemm_pipe, dim3(256), dim3(512), 0, stream, ab, ew, bias, out);
    }
}